// Round 1
// baseline (214.030 us; speedup 1.0000x reference)
//
#include <hip/hip_runtime.h>
#include <hip/hip_bf16.h>

#define NN 4096
#define FF 64
#define CC 512   // B*F = 8*64

typedef unsigned short u16;
typedef __attribute__((ext_vector_type(8))) short short8;
typedef __attribute__((ext_vector_type(4))) float f32x4;

typedef const void __attribute__((address_space(1)))* gas_t;
typedef void __attribute__((address_space(3)))* las_t;

__device__ __forceinline__ u16 f2bf(float x) {
  unsigned u = __float_as_uint(x);
  unsigned r = (u + 0x7FFFu + ((u >> 16) & 1)) >> 16;  // RNE
  return (u16)r;
}

// ---------------- K0: adj -> maskT bf16 [i][j], maskT[i][j] = (j<4095 && adj[j+1][i]>0) ----------------
__global__ __launch_bounds__(256) void k_maskT(const int* __restrict__ adj, u16* __restrict__ maskT) {
  __shared__ u16 tile[64][66];
  const int i0 = blockIdx.x * 64, j0 = blockIdx.y * 64;
  const int t = threadIdx.x, li = t & 63, lr = t >> 6;
#pragma unroll
  for (int rr = 0; rr < 64; rr += 4) {
    int j = j0 + rr + lr;
    u16 v = 0;
    if (j < NN - 1) v = (adj[(size_t)(j + 1) * NN + i0 + li] > 0) ? 0x3F80 : 0;  // bf16 1.0 / 0.0
    tile[li][rr + lr] = v;  // transpose in LDS
  }
  __syncthreads();
#pragma unroll
  for (int rr = 0; rr < 64; rr += 4) {
    int i = i0 + rr + lr;
    maskT[(size_t)i * NN + j0 + li] = tile[rr + lr][li];
  }
}

// ---------------- K1: h = inp @ W^T + b ; h[:,0,:]=0 ; hsum partial via atomics ----------------
__global__ __launch_bounds__(256) void k_h(const float* __restrict__ inp, const float* __restrict__ Ww,
                                           const float* __restrict__ Wb, float* __restrict__ h,
                                           float* __restrict__ hsum) {
  const int t = threadIdx.x, lane = t & 63, w = t >> 6;
  const int row0 = blockIdx.x * 64;          // flattened b*4096+n, 64 rows/block (same b)
  const int b = row0 >> 12;
  float wreg[64];
#pragma unroll
  for (int k = 0; k < 64; ++k) wreg[k] = Ww[lane * 64 + k];  // lane = output feature o
  const float bias = Wb[lane];
  float fsum = 0.f;
  for (int rr = 0; rr < 64; rr += 4) {
    int row = row0 + rr + w;
    float v = inp[(size_t)row * 64 + lane];
    float acc = bias;
#pragma unroll
    for (int k = 0; k < 64; ++k) acc += __shfl(v, k) * wreg[k];
    if ((row & (NN - 1)) == 0) acc = 0.f;    // h[:,0,:] = 0
    h[(size_t)row * 64 + lane] = acc;
    fsum += acc;
  }
  __shared__ float wsum[4][64];
  wsum[w][lane] = fsum;
  __syncthreads();
  if (w == 0)
    atomicAdd(&hsum[b * 64 + lane], wsum[0][lane] + wsum[1][lane] + wsum[2][lane] + wsum[3][lane]);
}

// ---------------- K1b: h -> h2t bf16 [b*64+f][j]  (K-major for GEMM B operand) ----------------
__global__ __launch_bounds__(256) void k_h2t(const float* __restrict__ h, u16* __restrict__ h2t) {
  __shared__ u16 tile[64][66];
  const int j0 = blockIdx.x * 64, b = blockIdx.y;
  const int t = threadIdx.x, lf = t & 63, lr = t >> 6;
#pragma unroll
  for (int rr = 0; rr < 64; rr += 4) {
    int j = j0 + rr + lr;
    tile[lf][rr + lr] = f2bf(h[((size_t)b * NN + j) * 64 + lf]);
  }
  __syncthreads();
#pragma unroll
  for (int rr = 0; rr < 64; rr += 4) {
    int f = rr + lr;
    h2t[((size_t)b * 64 + f) * NN + j0 + lf] = tile[f][lf];
  }
}

// ---------------- K2: M[i][c] = sum_j maskT[i][j] * h2t[c][j]   (bf16 MFMA, 128x128 tile, Ksplit=2) ----------------
__global__ __launch_bounds__(256) void k_gemm(const u16* __restrict__ A, const u16* __restrict__ Bm,
                                              float* __restrict__ M0, float* __restrict__ M1) {
  __shared__ __align__(16) u16 lA[128 * 32];
  __shared__ __align__(16) u16 lB[128 * 32];
  const int c0 = blockIdx.x * 128, i0 = blockIdx.y * 128, z = blockIdx.z;
  const int t = threadIdx.x, lane = t & 63, w = t >> 6;
  const int wr = w >> 1, wc = w & 1;

  // staging: each wave covers 2 x 1KB chunks per operand; lane l -> row (l>>2), kk 8*(l&3)
  const u16* gA0 = A + (size_t)(i0 + 32 * w + (lane >> 2)) * NN + (lane & 3) * 8 + z * 2048;
  const u16* gA1 = gA0 + (size_t)16 * NN;
  const u16* gB0 = Bm + (size_t)(c0 + 32 * w + (lane >> 2)) * NN + (lane & 3) * 8 + z * 2048;
  const u16* gB1 = gB0 + (size_t)16 * NN;
  char* dA0 = (char*)lA + (2 * w) * 1024;
  char* dA1 = dA0 + 1024;
  char* dB0 = (char*)lB + (2 * w) * 1024;
  char* dB1 = dB0 + 1024;

  f32x4 acc[4][4] = {};
  const int ra = wr * 64 + (lane & 15);
  const int rb = wc * 64 + (lane & 15);
  const int kk = (lane >> 4) * 8;

  for (int kt = 0; kt < 2048; kt += 32) {
    __builtin_amdgcn_global_load_lds((gas_t)(gA0 + kt), (las_t)dA0, 16, 0, 0);
    __builtin_amdgcn_global_load_lds((gas_t)(gA1 + kt), (las_t)dA1, 16, 0, 0);
    __builtin_amdgcn_global_load_lds((gas_t)(gB0 + kt), (las_t)dB0, 16, 0, 0);
    __builtin_amdgcn_global_load_lds((gas_t)(gB1 + kt), (las_t)dB1, 16, 0, 0);
    __syncthreads();
    short8 af[4], bf[4];
#pragma unroll
    for (int m = 0; m < 4; ++m) af[m] = *reinterpret_cast<const short8*>(&lA[(ra + m * 16) * 32 + kk]);
#pragma unroll
    for (int n = 0; n < 4; ++n) bf[n] = *reinterpret_cast<const short8*>(&lB[(rb + n * 16) * 32 + kk]);
#pragma unroll
    for (int m = 0; m < 4; ++m)
#pragma unroll
      for (int n = 0; n < 4; ++n)
        acc[m][n] = __builtin_amdgcn_mfma_f32_16x16x32_bf16(af[m], bf[n], acc[m][n], 0, 0, 0);
    __syncthreads();
  }
  float* Mout = z ? M1 : M0;
  const int orow = i0 + wr * 64 + (lane >> 4) * 4;  // C/D: col=lane&15, row=4*(lane>>4)+r (m89-verified)
  const int ocol = c0 + wc * 64 + (lane & 15);
#pragma unroll
  for (int m = 0; m < 4; ++m)
#pragma unroll
    for (int n = 0; n < 4; ++n)
#pragma unroll
      for (int r = 0; r < 4; ++r)
        Mout[(size_t)(orow + m * 16 + r) * CC + ocol + n * 16] = acc[m][n][r];
}

// ---------------- K3: s = h.a1 + (M0+M1).a2 ; s[:,0]=0 ; out = lrelu(s * hsum) ----------------
__global__ __launch_bounds__(256) void k_final(const float* __restrict__ h, const float* __restrict__ M0,
                                               const float* __restrict__ M1, const float* __restrict__ a,
                                               const float* __restrict__ hsum, float* __restrict__ out) {
  __shared__ float a1[64][65], a2[64][65];
  __shared__ float hs[64], sv[64];
  const int b = blockIdx.x >> 6;
  const int i0 = (blockIdx.x & 63) * 64;
  const int t = threadIdx.x;
  {
    const int lr = t >> 6, li = t & 63;
#pragma unroll
    for (int rr = 0; rr < 64; rr += 4) {
      a1[rr + lr][li] = a[(size_t)(rr + lr) * NN + i0 + li];
      a2[rr + lr][li] = a[(size_t)(64 + rr + lr) * NN + i0 + li];
    }
    if (t < 64) hs[t] = hsum[b * 64 + t];
  }
  __syncthreads();
  const int il = t >> 2, q = t & 3;
  const int i = i0 + il;
  const float* hrow = &h[((size_t)b * NN + i) * 64 + q * 16];
  const float* m0 = &M0[(size_t)i * CC + b * 64 + q * 16];
  const float* m1 = &M1[(size_t)i * CC + b * 64 + q * 16];
  float p = 0.f;
#pragma unroll
  for (int k = 0; k < 16; ++k) {
    int f = q * 16 + k;
    p += hrow[k] * a1[f][il];
    p += (m0[k] + m1[k]) * a2[f][il];
  }
  p += __shfl_down(p, 2, 4);
  p += __shfl_down(p, 1, 4);
  if (q == 0) sv[il] = (i == 0) ? 0.f : p;
  __syncthreads();
  const int lf = t & 63, lr = t >> 6;
#pragma unroll
  for (int rr = 0; rr < 64; rr += 4) {
    int ii = rr + lr;
    float val = sv[ii] * hs[lf];
    out[((size_t)b * NN + i0 + ii) * 64 + lf] = (val >= 0.f) ? val : 0.01f * val;
  }
}

extern "C" void kernel_launch(void* const* d_in, const int* in_sizes, int n_in,
                              void* d_out, int out_size, void* d_ws, size_t ws_size,
                              hipStream_t stream) {
  const float* inp = (const float*)d_in[0];
  const int* adj = (const int*)d_in[1];
  const float* Ww = (const float*)d_in[2];
  const float* Wb = (const float*)d_in[3];
  const float* a = (const float*)d_in[4];
  float* out = (float*)d_out;
  char* ws = (char*)d_ws;

  u16* maskT = (u16*)ws;                      // 32 MB  [4096][4096] bf16
  u16* h2t = (u16*)(ws + 33554432);           //  4 MB  [512][4096] bf16
  float* h = (float*)(ws + 37748736);         //  8 MB  [8][4096][64] f32
  float* hsum = (float*)(ws + 46137344);      //  2 KB  [8][64]
  float* M0 = (float*)(ws + 47185920);        //  8 MB  [4096][512] f32
  float* M1 = (float*)(ws + 55574528);        //  8 MB

  hipMemsetAsync(hsum, 0, 8 * 64 * sizeof(float), stream);
  hipLaunchKernelGGL(k_maskT, dim3(64, 64), dim3(256), 0, stream, adj, maskT);
  hipLaunchKernelGGL(k_h, dim3(512), dim3(256), 0, stream, inp, Ww, Wb, h, hsum);
  hipLaunchKernelGGL(k_h2t, dim3(64, 8), dim3(256), 0, stream, h, h2t);
  hipLaunchKernelGGL(k_gemm, dim3(4, 32, 2), dim3(256), 0, stream, maskT, h2t, M0, M1);
  hipLaunchKernelGGL(k_final, dim3(512), dim3(256), 0, stream, h, M0, M1, a, hsum, out);
}

// Round 4
// 162.642 us; speedup vs baseline: 1.3160x; 1.3160x over previous
//
#include <hip/hip_runtime.h>
#include <hip/hip_bf16.h>

#define NN 4096

typedef unsigned short u16;
typedef __attribute__((ext_vector_type(8))) short short8;
typedef __attribute__((ext_vector_type(4))) float f32x4;
typedef __attribute__((ext_vector_type(4))) unsigned short u16x4;
typedef __attribute__((ext_vector_type(8))) unsigned short u16x8;
typedef __attribute__((ext_vector_type(4))) int i32x4;

typedef const void __attribute__((address_space(1)))* gas_t;
typedef void __attribute__((address_space(3)))* las_t;

__device__ __forceinline__ u16 f2bf(float x) {
  unsigned u = __float_as_uint(x);
  return (u16)((u + 0x7FFFu + ((u >> 16) & 1)) >> 16);  // RNE
}

// ---------------- K0: adj -> maskT bf16 [i][j] = (j<4095 && adj[j+1][i]>0) ----------------
// 128x128 tile, int4 coalesced reads, LDS transpose, ushort4 coalesced writes.
__global__ __launch_bounds__(256) void k_maskT(const int* __restrict__ adj, u16* __restrict__ maskT) {
  __shared__ __align__(16) u16 tile[128 * 132];  // stride 132 u16 = 264B (8B-aligned rows)
  const int i0 = blockIdx.x * 128, j0 = blockIdx.y * 128;
  const int t = threadIdx.x;
  const int jr = t >> 5, ic = (t & 31) * 4;
#pragma unroll
  for (int pass = 0; pass < 16; ++pass) {
    const int jl = pass * 8 + jr;
    const int j = j0 + jl;
    u16 v0 = 0, v1 = 0, v2 = 0, v3 = 0;
    if (j < NN - 1) {
      i32x4 av = *reinterpret_cast<const i32x4*>(&adj[(size_t)(j + 1) * NN + i0 + ic]);
      v0 = av.x > 0 ? 0x3F80 : 0;
      v1 = av.y > 0 ? 0x3F80 : 0;
      v2 = av.z > 0 ? 0x3F80 : 0;
      v3 = av.w > 0 ? 0x3F80 : 0;
    }
    tile[(ic + 0) * 132 + jl] = v0;
    tile[(ic + 1) * 132 + jl] = v1;
    tile[(ic + 2) * 132 + jl] = v2;
    tile[(ic + 3) * 132 + jl] = v3;
  }
  __syncthreads();
  const int ir = t >> 5, jc = (t & 31) * 4;
#pragma unroll
  for (int pass = 0; pass < 16; ++pass) {
    const int il = pass * 8 + ir;
    u16x4 o = *reinterpret_cast<const u16x4*>(&tile[il * 132 + jc]);
    *reinterpret_cast<u16x4*>(&maskT[(size_t)(i0 + il) * NN + j0 + jc]) = o;
  }
}

// ---------------- K1: h = inp@W^T + b (bf16 MFMA); fused: h f32, h2t bf16 K-major, hsum ----------------
__global__ __launch_bounds__(256) void k_h(const float* __restrict__ inp, const float* __restrict__ Ww,
                                           const float* __restrict__ Wb, float* __restrict__ h,
                                           u16* __restrict__ h2t, float* __restrict__ hsum) {
  __shared__ __align__(16) u16 lA[128 * 64];  // inp tile bf16, XOR-swizzled k-blocks
  __shared__ __align__(16) u16 lW[64 * 64];   // W bf16 [o][k], XOR-swizzled
  const int t = threadIdx.x, lane = t & 63, w = t >> 6;
  const int bid = blockIdx.x;
  const int b = bid >> 5;
  const size_t row0 = (size_t)bid * 128;
  {
    const int o = t >> 2, k0 = (t & 3) * 16;
    const float* src = &Ww[o * 64 + k0];
    u16 tmp[16];
#pragma unroll
    for (int e = 0; e < 16; ++e) tmp[e] = f2bf(src[e]);
    const int swz = (o & 7) * 8;
#pragma unroll
    for (int v = 0; v < 2; ++v)
      *reinterpret_cast<u16x8*>(&lW[o * 64 + ((k0 + v * 8) ^ swz)]) = *reinterpret_cast<u16x8*>(&tmp[v * 8]);
  }
  {
    const int r = t >> 1, k0 = (t & 1) * 32;
    const float* src = &inp[(row0 + r) * 64 + k0];
    u16 tmp[32];
#pragma unroll
    for (int e = 0; e < 32; ++e) tmp[e] = f2bf(src[e]);
    const int swz = (r & 7) * 8;
#pragma unroll
    for (int v = 0; v < 4; ++v)
      *reinterpret_cast<u16x8*>(&lA[r * 64 + ((k0 + v * 8) ^ swz)]) = *reinterpret_cast<u16x8*>(&tmp[v * 8]);
  }
  __syncthreads();
  f32x4 acc[2][4] = {};
#pragma unroll
  for (int ks = 0; ks < 2; ++ks) {
    const int kk = ks * 32 + (lane >> 4) * 8;
    short8 af[2], bf[4];
#pragma unroll
    for (int m = 0; m < 2; ++m) {
      const int row = w * 32 + m * 16 + (lane & 15);
      af[m] = *reinterpret_cast<const short8*>(&lA[row * 64 + (kk ^ ((row & 7) * 8))]);
    }
#pragma unroll
    for (int n = 0; n < 4; ++n) {
      const int o = n * 16 + (lane & 15);
      bf[n] = *reinterpret_cast<const short8*>(&lW[o * 64 + (kk ^ ((o & 7) * 8))]);
    }
#pragma unroll
    for (int m = 0; m < 2; ++m)
#pragma unroll
      for (int n = 0; n < 4; ++n)
        acc[m][n] = __builtin_amdgcn_mfma_f32_16x16x32_bf16(af[m], bf[n], acc[m][n], 0, 0, 0);
  }
  // epilogue: bias, row-0 zero, h f32 store, h2t bf16 transposed store, hsum partials
  const int f0 = lane & 15;
  const int rsub = (lane >> 4) * 4;
  float wb[4];
#pragma unroll
  for (int n = 0; n < 4; ++n) wb[n] = Wb[n * 16 + f0];
  const int nloc_base = (bid & 31) * 128;
  float ps[4] = {0.f, 0.f, 0.f, 0.f};
#pragma unroll
  for (int m = 0; m < 2; ++m) {
    const int rl = w * 32 + m * 16 + rsub;
#pragma unroll
    for (int n = 0; n < 4; ++n) {
      u16 hb[4];
#pragma unroll
      for (int r = 0; r < 4; ++r) {
        float v = acc[m][n][r] + wb[n];
        if (nloc_base + rl + r == 0) v = 0.f;
        h[(row0 + rl + r) * 64 + n * 16 + f0] = v;
        hb[r] = f2bf(v);
        ps[n] += v;
      }
      *reinterpret_cast<u16x4*>(&h2t[(size_t)(b * 64 + n * 16 + f0) * NN + nloc_base + rl]) =
          *reinterpret_cast<u16x4*>(&hb[0]);
    }
  }
#pragma unroll
  for (int n = 0; n < 4; ++n) {
    float v = ps[n];
    v += __shfl_xor(v, 16);
    v += __shfl_xor(v, 32);
    if (lane < 16) atomicAdd(&hsum[b * 64 + n * 16 + f0], v);
  }
}

// ---------------- K2: fused GEMM: s[b,i] += sum_f a2[f,i] * sum_j maskT[i,j]*h2t[b*64+f,j] ----------------
// 128x128 tile, BK=64, Ksplit=8 (grid 4x32x8 = 1024 blocks = 4/CU), XOR-swizzled LDS via
// pre-swizzled global source (global_load_lds writes linearly).
__global__ __launch_bounds__(256, 4) void k_gemm(const u16* __restrict__ A, const u16* __restrict__ Bm,
                                                 const float* __restrict__ a, float* __restrict__ s) {
  __shared__ __align__(16) u16 lA[128 * 64];
  __shared__ __align__(16) u16 lB[128 * 64];
  const int c0 = blockIdx.x * 128, i0 = blockIdx.y * 128, z = blockIdx.z;
  const int t = threadIdx.x, lane = t & 63, w = t >> 6;
  const int wr = w >> 1, wc = w & 1;

  const int srow = lane >> 3;                  // row within 8-row chunk
  const int sk = ((lane & 7) ^ srow) * 8;      // pre-swizzled source k-offset (u16)
  const size_t kbase = (size_t)z * 512;
  const u16* gA = A + (size_t)(i0 + w * 32 + srow) * NN + kbase + sk;
  const u16* gB = Bm + (size_t)(c0 + w * 32 + srow) * NN + kbase + sk;

  f32x4 acc[4][4] = {};
  for (int kt = 0; kt < 512; kt += 64) {
#pragma unroll
    for (int c = 0; c < 4; ++c) {
      __builtin_amdgcn_global_load_lds((gas_t)(gA + (size_t)(8 * c) * NN + kt),
                                       (las_t)((char*)lA + (w * 32 + 8 * c) * 128 + lane * 16), 16, 0, 0);
      __builtin_amdgcn_global_load_lds((gas_t)(gB + (size_t)(8 * c) * NN + kt),
                                       (las_t)((char*)lB + (w * 32 + 8 * c) * 128 + lane * 16), 16, 0, 0);
    }
    __syncthreads();
#pragma unroll
    for (int ks = 0; ks < 2; ++ks) {
      const int kb = ks * 4 + (lane >> 4);  // global k-block 0..7 within BK=64
      short8 af[4], bf[4];
#pragma unroll
      for (int m = 0; m < 4; ++m) {
        const int row = wr * 64 + m * 16 + (lane & 15);
        af[m] = *reinterpret_cast<const short8*>(&lA[row * 64 + ((kb ^ (row & 7)) * 8)]);
      }
#pragma unroll
      for (int n = 0; n < 4; ++n) {
        const int row = wc * 64 + n * 16 + (lane & 15);
        bf[n] = *reinterpret_cast<const short8*>(&lB[row * 64 + ((kb ^ (row & 7)) * 8)]);
      }
#pragma unroll
      for (int m = 0; m < 4; ++m)
#pragma unroll
        for (int n = 0; n < 4; ++n)
          acc[m][n] = __builtin_amdgcn_mfma_f32_16x16x32_bf16(af[m], bf[n], acc[m][n], 0, 0, 0);
    }
    __syncthreads();
  }
  // fused epilogue: pp[i-row] = sum over f (cols) of acc * a2[f][i]; reduce over f-lanes; atomicAdd s
  const int b = blockIdx.x * 2 + wc;
  const int f0 = lane & 15, rsub = (lane >> 4) * 4;
  float pp[4][4];
#pragma unroll
  for (int m = 0; m < 4; ++m) {
    const int irow = i0 + wr * 64 + m * 16 + rsub;
#pragma unroll
    for (int r = 0; r < 4; ++r) pp[m][r] = 0.f;
#pragma unroll
    for (int n = 0; n < 4; ++n) {
      f32x4 a2v = *reinterpret_cast<const f32x4*>(&a[(size_t)(64 + n * 16 + f0) * NN + irow]);
#pragma unroll
      for (int r = 0; r < 4; ++r) pp[m][r] += acc[m][n][r] * a2v[r];
    }
  }
#pragma unroll
  for (int m = 0; m < 4; ++m)
#pragma unroll
    for (int r = 0; r < 4; ++r) {
      float v = pp[m][r];
      v += __shfl_xor(v, 1);
      v += __shfl_xor(v, 2);
      v += __shfl_xor(v, 4);
      v += __shfl_xor(v, 8);
      pp[m][r] = v;
    }
  if (f0 == 0) {
    const int irow = i0 + wr * 64 + rsub;
#pragma unroll
    for (int m = 0; m < 4; ++m)
#pragma unroll
      for (int r = 0; r < 4; ++r)
        atomicAdd(&s[(size_t)b * NN + irow + m * 16 + r], pp[m][r]);
  }
}

// ---------------- K3: s_tot = h.a1 + s_gemm; s[:,0]=0; out = lrelu(s_tot * hsum) ----------------
__global__ __launch_bounds__(256) void k_final(const float* __restrict__ h, const float* __restrict__ sg,
                                               const float* __restrict__ a, const float* __restrict__ hsum,
                                               float* __restrict__ out) {
  __shared__ float a1[64][65];
  __shared__ float hs[64], sv[64];
  const int b = blockIdx.x >> 6;
  const int i0 = (blockIdx.x & 63) * 64;
  const int t = threadIdx.x;
  {
    const int lr = t >> 6, li = t & 63;
#pragma unroll
    for (int rr = 0; rr < 64; rr += 4)
      a1[rr + lr][li] = a[(size_t)(rr + lr) * NN + i0 + li];
    if (t < 64) hs[t] = hsum[b * 64 + t];
  }
  __syncthreads();
  const int il = t >> 2, q = t & 3;
  const int i = i0 + il;
  const float* hrow = &h[((size_t)b * NN + i) * 64 + q * 16];
  float p = 0.f;
#pragma unroll
  for (int k = 0; k < 16; ++k) p += hrow[k] * a1[q * 16 + k][il];
  p += __shfl_down(p, 2, 4);
  p += __shfl_down(p, 1, 4);
  if (q == 0) sv[il] = (i == 0) ? 0.f : (p + sg[(size_t)b * NN + i]);
  __syncthreads();
  const int lf = t & 63, lr2 = t >> 6;
#pragma unroll
  for (int rr = 0; rr < 64; rr += 4) {
    int ii = rr + lr2;
    float val = sv[ii] * hs[lf];
    out[((size_t)b * NN + i0 + ii) * 64 + lf] = (val >= 0.f) ? val : 0.01f * val;
  }
}

extern "C" void kernel_launch(void* const* d_in, const int* in_sizes, int n_in,
                              void* d_out, int out_size, void* d_ws, size_t ws_size,
                              hipStream_t stream) {
  const float* inp = (const float*)d_in[0];
  const int* adj = (const int*)d_in[1];
  const float* Ww = (const float*)d_in[2];
  const float* Wb = (const float*)d_in[3];
  const float* a = (const float*)d_in[4];
  float* out = (float*)d_out;
  char* ws = (char*)d_ws;

  float* s = (float*)ws;                              // 128 KB [8][4096] f32
  float* hsum = (float*)(ws + 131072);                //   2 KB [8][64] f32
  u16* maskT = (u16*)(ws + 262144);                   //  32 MB [4096][4096] bf16
  u16* h2t = (u16*)(ws + 262144 + 33554432);          //   4 MB [512][4096] bf16
  float* h = (float*)(ws + 262144 + 33554432 + 4194304);  // 8 MB [8*4096][64] f32

  hipMemsetAsync(ws, 0, 133120, stream);  // zero s + hsum
  hipLaunchKernelGGL(k_maskT, dim3(32, 32), dim3(256), 0, stream, adj, maskT);
  hipLaunchKernelGGL(k_h, dim3(256), dim3(256), 0, stream, inp, Ww, Wb, h, h2t, hsum);
  hipLaunchKernelGGL(k_gemm, dim3(4, 32, 8), dim3(256), 0, stream, maskT, h2t, a, s);
  hipLaunchKernelGGL(k_final, dim3(512), dim3(256), 0, stream, h, s, a, hsum, out);
}

// Round 5
// 152.413 us; speedup vs baseline: 1.4043x; 1.0671x over previous
//
#include <hip/hip_runtime.h>
#include <hip/hip_bf16.h>

#define NN 4096

typedef unsigned short u16;
typedef __attribute__((ext_vector_type(8))) short short8;
typedef __attribute__((ext_vector_type(4))) float f32x4;
typedef __attribute__((ext_vector_type(4))) unsigned short u16x4;
typedef __attribute__((ext_vector_type(8))) unsigned short u16x8;
typedef __attribute__((ext_vector_type(4))) int i32x4;

typedef const void __attribute__((address_space(1)))* gas_t;
typedef void __attribute__((address_space(3)))* las_t;

__device__ __forceinline__ u16 f2bf(float x) {
  unsigned u = __float_as_uint(x);
  return (u16)((u + 0x7FFFu + ((u >> 16) & 1)) >> 16);  // RNE
}

// ---------------- K0: adj -> maskT bf16 [i][j] = (j<4095 && adj[j+1][i]>0) ----------------
__global__ __launch_bounds__(256) void k_maskT(const int* __restrict__ adj, u16* __restrict__ maskT) {
  __shared__ __align__(16) u16 tile[128 * 132];
  const int i0 = blockIdx.x * 128, j0 = blockIdx.y * 128;
  const int t = threadIdx.x;
  const int jr = t >> 5, ic = (t & 31) * 4;
#pragma unroll
  for (int pass = 0; pass < 16; ++pass) {
    const int jl = pass * 8 + jr;
    const int j = j0 + jl;
    u16 v0 = 0, v1 = 0, v2 = 0, v3 = 0;
    if (j < NN - 1) {
      i32x4 av = *reinterpret_cast<const i32x4*>(&adj[(size_t)(j + 1) * NN + i0 + ic]);
      v0 = av.x > 0 ? 0x3F80 : 0;
      v1 = av.y > 0 ? 0x3F80 : 0;
      v2 = av.z > 0 ? 0x3F80 : 0;
      v3 = av.w > 0 ? 0x3F80 : 0;
    }
    tile[(ic + 0) * 132 + jl] = v0;
    tile[(ic + 1) * 132 + jl] = v1;
    tile[(ic + 2) * 132 + jl] = v2;
    tile[(ic + 3) * 132 + jl] = v3;
  }
  __syncthreads();
  const int ir = t >> 5, jc = (t & 31) * 4;
#pragma unroll
  for (int pass = 0; pass < 16; ++pass) {
    const int il = pass * 8 + ir;
    u16x4 o = *reinterpret_cast<const u16x4*>(&tile[il * 132 + jc]);
    *reinterpret_cast<u16x4*>(&maskT[(size_t)(i0 + il) * NN + j0 + jc]) = o;
  }
}

// ---------------- K1: h = inp@W^T + b (bf16 MFMA); fused: h f32, h2t bf16 K-major, hsum ----------------
__global__ __launch_bounds__(256) void k_h(const float* __restrict__ inp, const float* __restrict__ Ww,
                                           const float* __restrict__ Wb, float* __restrict__ h,
                                           u16* __restrict__ h2t, float* __restrict__ hsum) {
  __shared__ __align__(16) u16 lA[128 * 64];
  __shared__ __align__(16) u16 lW[64 * 64];
  const int t = threadIdx.x, lane = t & 63, w = t >> 6;
  const int bid = blockIdx.x;
  const int b = bid >> 5;
  const size_t row0 = (size_t)bid * 128;
  {
    const int o = t >> 2, k0 = (t & 3) * 16;
    const float* src = &Ww[o * 64 + k0];
    u16 tmp[16];
#pragma unroll
    for (int e = 0; e < 16; ++e) tmp[e] = f2bf(src[e]);
    const int swz = (o & 7) * 8;
#pragma unroll
    for (int v = 0; v < 2; ++v)
      *reinterpret_cast<u16x8*>(&lW[o * 64 + ((k0 + v * 8) ^ swz)]) = *reinterpret_cast<u16x8*>(&tmp[v * 8]);
  }
  {
    const int r = t >> 1, k0 = (t & 1) * 32;
    const float* src = &inp[(row0 + r) * 64 + k0];
    u16 tmp[32];
#pragma unroll
    for (int e = 0; e < 32; ++e) tmp[e] = f2bf(src[e]);
    const int swz = (r & 7) * 8;
#pragma unroll
    for (int v = 0; v < 4; ++v)
      *reinterpret_cast<u16x8*>(&lA[r * 64 + ((k0 + v * 8) ^ swz)]) = *reinterpret_cast<u16x8*>(&tmp[v * 8]);
  }
  __syncthreads();
  f32x4 acc[2][4] = {};
#pragma unroll
  for (int ks = 0; ks < 2; ++ks) {
    const int kk = ks * 32 + (lane >> 4) * 8;
    short8 af[2], bf[4];
#pragma unroll
    for (int m = 0; m < 2; ++m) {
      const int row = w * 32 + m * 16 + (lane & 15);
      af[m] = *reinterpret_cast<const short8*>(&lA[row * 64 + (kk ^ ((row & 7) * 8))]);
    }
#pragma unroll
    for (int n = 0; n < 4; ++n) {
      const int o = n * 16 + (lane & 15);
      bf[n] = *reinterpret_cast<const short8*>(&lW[o * 64 + (kk ^ ((o & 7) * 8))]);
    }
#pragma unroll
    for (int m = 0; m < 2; ++m)
#pragma unroll
      for (int n = 0; n < 4; ++n)
        acc[m][n] = __builtin_amdgcn_mfma_f32_16x16x32_bf16(af[m], bf[n], acc[m][n], 0, 0, 0);
  }
  const int f0 = lane & 15;
  const int rsub = (lane >> 4) * 4;
  float wb[4];
#pragma unroll
  for (int n = 0; n < 4; ++n) wb[n] = Wb[n * 16 + f0];
  const int nloc_base = (bid & 31) * 128;
  float ps[4] = {0.f, 0.f, 0.f, 0.f};
#pragma unroll
  for (int m = 0; m < 2; ++m) {
    const int rl = w * 32 + m * 16 + rsub;
#pragma unroll
    for (int n = 0; n < 4; ++n) {
      u16 hb[4];
#pragma unroll
      for (int r = 0; r < 4; ++r) {
        float v = acc[m][n][r] + wb[n];
        if (nloc_base + rl + r == 0) v = 0.f;
        h[(row0 + rl + r) * 64 + n * 16 + f0] = v;
        hb[r] = f2bf(v);
        ps[n] += v;
      }
      *reinterpret_cast<u16x4*>(&h2t[(size_t)(b * 64 + n * 16 + f0) * NN + nloc_base + rl]) =
          *reinterpret_cast<u16x4*>(&hb[0]);
    }
  }
#pragma unroll
  for (int n = 0; n < 4; ++n) {
    float v = ps[n];
    v += __shfl_xor(v, 16);
    v += __shfl_xor(v, 32);
    if (lane < 16) atomicAdd(&hsum[b * 64 + n * 16 + f0], v);
  }
}

// ---------------- K2: fused GEMM, 2-phase double-buffered, XCD-chunk swizzled ----------------
// s[b,i] += sum_f a2[f,i] * sum_j maskT[i,j]*h2t[b*64+f,j]
// 128x128 tile, BK=64, Ksplit=4 -> 512 blocks (2/CU at 64 KB LDS). Per iter: prefetch next
// K-tile via global_load_lds, compute current from the other buffer, ONE barrier.
__global__ __launch_bounds__(256, 2) void k_gemm(const u16* __restrict__ A, const u16* __restrict__ Bm,
                                                 const float* __restrict__ a, float* __restrict__ s) {
  __shared__ __align__(16) u16 lA0[128 * 64], lA1[128 * 64];
  __shared__ __align__(16) u16 lB0[128 * 64], lB1[128 * 64];
  // XCD-chunk swizzle: consecutive hardware slots round-robin XCDs; remap so each XCD gets
  // 64 consecutive logical ids -> the 4 c-blocks of one (i0,z) A-slab share an XCD L2.
  const int sid = blockIdx.x;                       // 0..511
  const int wgid = (sid & 7) * 64 + (sid >> 3);     // bijective (512 % 8 == 0)
  const int c0 = (wgid & 3) * 128;
  const int i0 = ((wgid >> 2) & 31) * 128;
  const int z = wgid >> 7;                          // 0..3
  const int t = threadIdx.x, lane = t & 63, w = t >> 6;
  const int wr = w >> 1, wc = w & 1;

  const int srow = lane >> 3;                  // row within 8-row chunk
  const int sk = ((lane & 7) ^ srow) * 8;      // pre-swizzled source k-offset (u16)
  const size_t kbase = (size_t)z * 1024;
  const u16* gA = A + (size_t)(i0 + w * 32 + srow) * NN + kbase + sk;
  const u16* gB = Bm + (size_t)(c0 + w * 32 + srow) * NN + kbase + sk;

#define STAGE_K(dstA, dstB, kt)                                                              \
  do {                                                                                       \
    _Pragma("unroll") for (int c = 0; c < 4; ++c) {                                          \
      __builtin_amdgcn_global_load_lds((gas_t)(gA + (size_t)(8 * c) * NN + (kt)),            \
                                       (las_t)((dstA) + (w * 32 + 8 * c) * 128 + lane * 16), \
                                       16, 0, 0);                                            \
      __builtin_amdgcn_global_load_lds((gas_t)(gB + (size_t)(8 * c) * NN + (kt)),            \
                                       (las_t)((dstB) + (w * 32 + 8 * c) * 128 + lane * 16), \
                                       16, 0, 0);                                            \
    }                                                                                        \
  } while (0)

  f32x4 acc[4][4] = {};
  STAGE_K((char*)lA0, (char*)lB0, 0);
  __syncthreads();  // vmcnt(0) drain + join
#pragma unroll 1
  for (int it = 0; it < 16; ++it) {
    char* nA = (it & 1) ? (char*)lA0 : (char*)lA1;
    char* nB = (it & 1) ? (char*)lB0 : (char*)lB1;
    if (it < 15) STAGE_K(nA, nB, (it + 1) * 64);   // prefetch next K-tile
    const u16* cA = (it & 1) ? lA1 : lA0;
    const u16* cB = (it & 1) ? lB1 : lB0;
#pragma unroll
    for (int ks = 0; ks < 2; ++ks) {
      const int kb = ks * 4 + (lane >> 4);
      short8 af[4], bfr[4];
#pragma unroll
      for (int m = 0; m < 4; ++m) {
        const int row = wr * 64 + m * 16 + (lane & 15);
        af[m] = *reinterpret_cast<const short8*>(&cA[row * 64 + ((kb ^ (row & 7)) * 8)]);
      }
#pragma unroll
      for (int n = 0; n < 4; ++n) {
        const int row = wc * 64 + n * 16 + (lane & 15);
        bfr[n] = *reinterpret_cast<const short8*>(&cB[row * 64 + ((kb ^ (row & 7)) * 8)]);
      }
#pragma unroll
      for (int m = 0; m < 4; ++m)
#pragma unroll
        for (int n = 0; n < 4; ++n)
          acc[m][n] = __builtin_amdgcn_mfma_f32_16x16x32_bf16(af[m], bfr[n], acc[m][n], 0, 0, 0);
    }
    __syncthreads();  // drains prefetch vmcnt + protects buffer swap
  }
#undef STAGE_K
  // fused epilogue: contract cols (f) with a2[f][i], reduce over f-lanes, atomicAdd into s
  const int b = (c0 >> 7) * 2 + wc;
  const int f0 = lane & 15, rsub = (lane >> 4) * 4;
  float pp[4][4];
#pragma unroll
  for (int m = 0; m < 4; ++m) {
    const int irow = i0 + wr * 64 + m * 16 + rsub;
#pragma unroll
    for (int r = 0; r < 4; ++r) pp[m][r] = 0.f;
#pragma unroll
    for (int n = 0; n < 4; ++n) {
      f32x4 a2v = *reinterpret_cast<const f32x4*>(&a[(size_t)(64 + n * 16 + f0) * NN + irow]);
#pragma unroll
      for (int r = 0; r < 4; ++r) pp[m][r] += acc[m][n][r] * a2v[r];
    }
  }
#pragma unroll
  for (int m = 0; m < 4; ++m)
#pragma unroll
    for (int r = 0; r < 4; ++r) {
      float v = pp[m][r];
      v += __shfl_xor(v, 1);
      v += __shfl_xor(v, 2);
      v += __shfl_xor(v, 4);
      v += __shfl_xor(v, 8);
      pp[m][r] = v;
    }
  if (f0 == 0) {
    const int irow = i0 + wr * 64 + rsub;
#pragma unroll
    for (int m = 0; m < 4; ++m)
#pragma unroll
      for (int r = 0; r < 4; ++r)
        atomicAdd(&s[(size_t)b * NN + irow + m * 16 + r], pp[m][r]);
  }
}

// ---------------- K3: s_tot = h.a1 + s_gemm; s[:,0]=0; out = lrelu(s_tot * hsum) ----------------
__global__ __launch_bounds__(256) void k_final(const float* __restrict__ h, const float* __restrict__ sg,
                                               const float* __restrict__ a, const float* __restrict__ hsum,
                                               float* __restrict__ out) {
  __shared__ float a1[64][65];
  __shared__ float hs[64], sv[64];
  const int b = blockIdx.x >> 6;
  const int i0 = (blockIdx.x & 63) * 64;
  const int t = threadIdx.x;
  {
    const int lr = t >> 6, li = t & 63;
#pragma unroll
    for (int rr = 0; rr < 64; rr += 4)
      a1[rr + lr][li] = a[(size_t)(rr + lr) * NN + i0 + li];
    if (t < 64) hs[t] = hsum[b * 64 + t];
  }
  __syncthreads();
  const int il = t >> 2, q = t & 3;
  const int i = i0 + il;
  const float* hrow = &h[((size_t)b * NN + i) * 64 + q * 16];
  float p = 0.f;
#pragma unroll
  for (int k = 0; k < 16; ++k) p += hrow[k] * a1[q * 16 + k][il];
  p += __shfl_down(p, 2, 4);
  p += __shfl_down(p, 1, 4);
  if (q == 0) sv[il] = (i == 0) ? 0.f : (p + sg[(size_t)b * NN + i]);
  __syncthreads();
  const int lf = t & 63, lr2 = t >> 6;
#pragma unroll
  for (int rr = 0; rr < 64; rr += 4) {
    int ii = rr + lr2;
    float val = sv[ii] * hs[lf];
    out[((size_t)b * NN + i0 + ii) * 64 + lf] = (val >= 0.f) ? val : 0.01f * val;
  }
}

extern "C" void kernel_launch(void* const* d_in, const int* in_sizes, int n_in,
                              void* d_out, int out_size, void* d_ws, size_t ws_size,
                              hipStream_t stream) {
  const float* inp = (const float*)d_in[0];
  const int* adj = (const int*)d_in[1];
  const float* Ww = (const float*)d_in[2];
  const float* Wb = (const float*)d_in[3];
  const float* a = (const float*)d_in[4];
  float* out = (float*)d_out;
  char* ws = (char*)d_ws;

  float* s = (float*)ws;                              // 128 KB [8][4096] f32
  float* hsum = (float*)(ws + 131072);                //   2 KB [8][64] f32
  u16* maskT = (u16*)(ws + 262144);                   //  32 MB [4096][4096] bf16
  u16* h2t = (u16*)(ws + 262144 + 33554432);          //   4 MB [512][4096] bf16
  float* h = (float*)(ws + 262144 + 33554432 + 4194304);  // 8 MB [8*4096][64] f32

  hipMemsetAsync(ws, 0, 133120, stream);  // zero s + hsum
  hipLaunchKernelGGL(k_maskT, dim3(32, 32), dim3(256), 0, stream, adj, maskT);
  hipLaunchKernelGGL(k_h, dim3(256), dim3(256), 0, stream, inp, Ww, Wb, h, h2t, hsum);
  hipLaunchKernelGGL(k_gemm, dim3(512), dim3(256), 0, stream, maskT, h2t, a, s);
  hipLaunchKernelGGL(k_final, dim3(512), dim3(256), 0, stream, h, s, a, hsum, out);
}